// Round 10
// baseline (13446.115 us; speedup 1.0000x reference)
//
#include <hip/hip_runtime.h>

#define T_STEPS 2048
#define BATCH   32
#define DIM     512
#define HID     512
#define NBK     16          // recurrence blocks; NBK * 32 cols == HID (!)
#define NB_FALLBACK 256
#define NTHR    512
#define NKS     8
#define WSTRIDE_F 1028      // fallback fused [Wih|Whh] rows
#define HSTRIDE 36
#define MROWS   (T_STEPS * BATCH)   // 65536
#define NCOLS   (4 * HID)           // 2048

// ws layout: [0,128K) mailbox region (MFMA path: first 64K bf16 [2][b][col];
//            fallback: fp32 [2][col][b]) | [128K,132K) tags/barrier | [132K,..) x_proj
#define BARR_OFF     (128 * 1024)
#define XP_OFF       (132 * 1024)
#define XP_BYTES     ((size_t)MROWS * NCOLS * 2)

#define FMA4(A, W, P) do { A.x = fmaf(W.x, P.x, A.x); A.y = fmaf(W.y, P.y, A.y); \
                           A.z = fmaf(W.z, P.z, A.z); A.w = fmaf(W.w, P.w, A.w); } while (0)
#define FMAS(A, s, P) do { A.x = fmaf(s, P.x, A.x); A.y = fmaf(s, P.y, A.y); \
                           A.z = fmaf(s, P.z, A.z); A.w = fmaf(s, P.w, A.w); } while (0)

#define LLC_LOAD4(dst, p) \
    asm volatile("global_load_dwordx4 %0, %1, off sc0 sc1" : "=v"(dst) : "v"(p) : "memory")
#define LLC_LOAD4_OFF(dst, p, imm) \
    asm volatile("global_load_dwordx4 %0, %1, off offset:" #imm " sc0 sc1" \
                 : "=v"(dst) : "v"(p) : "memory")
#define LLC_LOADD(dst, p) \
    asm volatile("global_load_dword %0, %1, off sc0 sc1" : "=v"(dst) : "v"(p) : "memory")
#define LLC_STORE1(p, v) \
    asm volatile("global_store_dword %0, %1, off sc0 sc1" :: "v"(p), "v"(v) : "memory")
#define LLC_STORE2(p, v) \
    asm volatile("global_store_dwordx2 %0, %1, off sc0 sc1" :: "v"(p), "v"(v) : "memory")

#define B2F(s) __uint_as_float(((unsigned)(unsigned short)(s)) << 16)

__device__ __forceinline__ float hsum4(float4 a) { return (a.x + a.y) + (a.z + a.w); }
__device__ __forceinline__ float sigm(float x) { return 1.f / (1.f + __expf(-x)); }

__device__ __forceinline__ unsigned short f2b(float f) {  // fp32 -> bf16 RNE
    unsigned u = __float_as_uint(f);
    return (unsigned short)((u + 0x7fffu + ((u >> 16) & 1u)) >> 16);
}

using s8v = __attribute__((ext_vector_type(8))) short;
using f4v = __attribute__((ext_vector_type(4))) float;

// ============================================================================
// Kernel 1: x_proj[M=T*B][N=4H] = x[M][512] * Wih^T  (proven R5-R8)
// ============================================================================
__global__ __launch_bounds__(256, 2) void xproj_gemm(
    const float* __restrict__ x, const float* __restrict__ Wih,
    unsigned short* __restrict__ xp)
{
    __shared__ unsigned short As[64][40];
    __shared__ unsigned short Bs[64][40];
    const int tid  = threadIdx.x;
    const int mi   = blockIdx.x >> 5;
    const int ni   = blockIdx.x & 31;
    const int lane = tid & 63;
    const int wv   = tid >> 6;
    const int wr   = (wv >> 1) * 32, wc = (wv & 1) * 32;
    const int r0   = lane & 15, kb = (lane >> 4) * 8;

    f4v acc00 = {0,0,0,0}, acc01 = {0,0,0,0}, acc10 = {0,0,0,0}, acc11 = {0,0,0,0};

    for (int ko = 0; ko < 512; ko += 32) {
        __syncthreads();
#pragma unroll
        for (int i = tid; i < 512; i += 256) {
            int row = i >> 3, kq = i & 7;
            float4 va = *(const float4*)(x   + (size_t)(mi * 64 + row) * 512 + ko + kq * 4);
            float4 vb = *(const float4*)(Wih + (size_t)(ni * 64 + row) * 512 + ko + kq * 4);
            uint2 ua = make_uint2((unsigned)f2b(va.x) | ((unsigned)f2b(va.y) << 16),
                                  (unsigned)f2b(va.z) | ((unsigned)f2b(va.w) << 16));
            uint2 ub = make_uint2((unsigned)f2b(vb.x) | ((unsigned)f2b(vb.y) << 16),
                                  (unsigned)f2b(vb.z) | ((unsigned)f2b(vb.w) << 16));
            *(uint2*)&As[row][kq * 4] = ua;
            *(uint2*)&Bs[row][kq * 4] = ub;
        }
        __syncthreads();
        s8v a0 = *(const s8v*)&As[wr      + r0][kb];
        s8v a1 = *(const s8v*)&As[wr + 16 + r0][kb];
        s8v b0 = *(const s8v*)&Bs[wc      + r0][kb];
        s8v b1 = *(const s8v*)&Bs[wc + 16 + r0][kb];
        acc00 = __builtin_amdgcn_mfma_f32_16x16x32_bf16(a0, b0, acc00, 0, 0, 0);
        acc01 = __builtin_amdgcn_mfma_f32_16x16x32_bf16(a0, b1, acc01, 0, 0, 0);
        acc10 = __builtin_amdgcn_mfma_f32_16x16x32_bf16(a1, b0, acc10, 0, 0, 0);
        acc11 = __builtin_amdgcn_mfma_f32_16x16x32_bf16(a1, b1, acc11, 0, 0, 0);
    }
    const int rb = (lane >> 4) * 4, cb = lane & 15;
#pragma unroll
    for (int j = 0; j < 4; ++j) {
        size_t rA = (size_t)(mi * 64 + wr + rb + j) * NCOLS + (ni * 64 + wc + cb);
        size_t rB = (size_t)(mi * 64 + wr + 16 + rb + j) * NCOLS + (ni * 64 + wc + cb);
        xp[rA]        = f2b(acc00[j]);
        xp[rA + 16]   = f2b(acc01[j]);
        xp[rB]        = f2b(acc10[j]);
        xp[rB + 16]   = f2b(acc11[j]);
    }
}

// ============================================================================
// Kernel 2: 16-block MFMA recurrence. NBK(16) x 32 cols == HID(512).
// 8 waves = (cg:2 col-half) x (ng:2 batch-half) x (ks2:2 K-half).
// Whh resident as bf16 A-frags (128 VGPR); B-frags (h) loaded DIRECTLY from
// the bf16 LLC mailbox (no LDS staging); K-half exchange via scalar LDS;
// gates per-lane (i,f,g,o of one (col,b) in one lane); tag-store sync.
// ============================================================================
__global__ __launch_bounds__(NTHR, 2) void lstm_mfma(
    const unsigned short* __restrict__ xp,   // [T*B][4H] bf16
    const float* __restrict__ Whh,
    const float* __restrict__ bih, const float* __restrict__ bhh,
    float* __restrict__ out,
    unsigned short* hb16, int* tags)         // hb16[2][B][H] bf16; tags[NBK*16]
{
    __shared__ float comb[4][16][66];        // [quadrant][gate*4+reg][lane] 16.9 KB

    const int tid   = threadIdx.x;
    const int bj    = blockIdx.x;            // 0..15
    const int lane  = tid & 63;
    const int wv    = tid >> 6;
    const int q     = wv & 3;                // quadrant
    const int ks2   = wv >> 2;               // K half (0/1)
    const int cg    = q >> 1, ng = q & 1;
    const int C0    = bj * 32;               // 16 * 32 == 512 == HID
    const int r0    = lane & 15;
    const int l16   = lane >> 4;
    const int blane = ng * 16 + r0;          // batch index (D: N = lane&15)
    const int c0col = C0 + cg * 16 + l16 * 4; // lane's 4 cols (D: M = (lane>>4)*4+reg)

    // ---- one-time: Whh -> bf16 A-frags (4 gates x 8 K-chunks of this K-half) ----
    s8v aw[4][8];
#pragma unroll
    for (int g = 0; g < 4; ++g) {
#pragma unroll
        for (int kc = 0; kc < 8; ++kc) {
            int R = g * 512 + C0 + cg * 16 + r0;         // <= 2047
            int k = ks2 * 256 + kc * 32 + l16 * 8;       // <= 504
            const float* wp = Whh + (size_t)R * 512 + k;
            float4 a = *(const float4*)wp;
            float4 b = *(const float4*)(wp + 4);
            s8v f;
            f[0] = (short)f2b(a.x); f[1] = (short)f2b(a.y);
            f[2] = (short)f2b(a.z); f[3] = (short)f2b(a.w);
            f[4] = (short)f2b(b.x); f[5] = (short)f2b(b.y);
            f[6] = (short)f2b(b.z); f[7] = (short)f2b(b.w);
            aw[g][kc] = f;
        }
    }
    float bs[4][4];
    float cst[4] = {0.f, 0.f, 0.f, 0.f};
    if (ks2 == 0) {
#pragma unroll
        for (int g = 0; g < 4; ++g)
#pragma unroll
            for (int r = 0; r < 4; ++r) {
                int c = g * 512 + c0col + r;
                bs[g][r] = bih[c] + bhh[c];
            }
    }

    for (int t = 0; t < T_STEPS; ++t) {
        // ---- xp prefetch (primary waves), issued before poll ----
        short4 ux0, ux1, ux2, ux3;
        if (ks2 == 0) {
            const unsigned short* xpp = xp + ((size_t)t * BATCH + blane) * NCOLS + c0col;
            ux0 = *(const short4*)(xpp);
            ux1 = *(const short4*)(xpp + 512);
            ux2 = *(const short4*)(xpp + 1024);
            ux3 = *(const short4*)(xpp + 1536);
        }

        // ---- wave-0-only poll over NBK tag lines, then barrier release ----
        if (tid < 64) {
            const int* tp = tags + ((lane & (NBK - 1)) << 4);
            while (true) {
                int tg;
                LLC_LOADD(tg, tp);
                asm volatile("s_waitcnt vmcnt(0)" ::: "memory");
                if (__all(tg >= t)) break;
                __builtin_amdgcn_s_sleep(1);
            }
        }
        __syncthreads();

        // ---- B-frags: h (bf16) DIRECT from LLC mailbox, 8 x 16B per lane ----
        uint4 bfr[8];
        {
            const unsigned short* hs = hb16 + (size_t)(t & 1) * (BATCH * HID) +
                                       (size_t)blane * HID + ks2 * 256 + l16 * 8;
            LLC_LOAD4_OFF(bfr[0], hs, 0);
            LLC_LOAD4_OFF(bfr[1], hs, 64);
            LLC_LOAD4_OFF(bfr[2], hs, 128);
            LLC_LOAD4_OFF(bfr[3], hs, 192);
            LLC_LOAD4_OFF(bfr[4], hs, 256);
            LLC_LOAD4_OFF(bfr[5], hs, 320);
            LLC_LOAD4_OFF(bfr[6], hs, 384);
            LLC_LOAD4_OFF(bfr[7], hs, 448);
            asm volatile("s_waitcnt vmcnt(0)" ::: "memory");
            __builtin_amdgcn_sched_barrier(0);
        }

        // ---- MFMA: 4 gates x 8 K-chunks (this wave's K-half) ----
        f4v acc0 = {0,0,0,0}, acc1 = {0,0,0,0}, acc2 = {0,0,0,0}, acc3 = {0,0,0,0};
#pragma unroll
        for (int kc = 0; kc < 8; ++kc) {
            s8v bf = *(const s8v*)&bfr[kc];
            acc0 = __builtin_amdgcn_mfma_f32_16x16x32_bf16(aw[0][kc], bf, acc0, 0, 0, 0);
            acc1 = __builtin_amdgcn_mfma_f32_16x16x32_bf16(aw[1][kc], bf, acc1, 0, 0, 0);
            acc2 = __builtin_amdgcn_mfma_f32_16x16x32_bf16(aw[2][kc], bf, acc2, 0, 0, 0);
            acc3 = __builtin_amdgcn_mfma_f32_16x16x32_bf16(aw[3][kc], bf, acc3, 0, 0, 0);
        }

        // ---- K-half exchange: scalar b32, lane-consecutive (conflict-free) ----
        if (ks2 == 1) {
#pragma unroll
            for (int j = 0; j < 4; ++j) {
                comb[q][0  + j][lane] = acc0[j];
                comb[q][4  + j][lane] = acc1[j];
                comb[q][8  + j][lane] = acc2[j];
                comb[q][12 + j][lane] = acc3[j];
            }
        }
        __syncthreads();

        // ---- gates (primary waves): per-lane, pure VALU ----
        if (ks2 == 0) {
            float hv[4];
#pragma unroll
            for (int j = 0; j < 4; ++j) {
                float gi = acc0[j] + comb[q][0  + j][lane] + bs[0][j] + B2F(((short*)&ux0)[j]);
                float gf = acc1[j] + comb[q][4  + j][lane] + bs[1][j] + B2F(((short*)&ux1)[j]);
                float gg = acc2[j] + comb[q][8  + j][lane] + bs[2][j] + B2F(((short*)&ux2)[j]);
                float go = acc3[j] + comb[q][12 + j][lane] + bs[3][j] + B2F(((short*)&ux3)[j]);
                float ig = sigm(gi), fg = sigm(gf), og = sigm(go);
                float g  = tanhf(gg);
                float c  = fg * cst[j] + ig * g;
                cst[j] = c;
                hv[j] = og * tanhf(c);
            }
            // publish bf16 h: one dwordx2 per lane into mailbox [b][col]
            uint2 pk;
            pk.x = (unsigned)f2b(hv[0]) | ((unsigned)f2b(hv[1]) << 16);
            pk.y = (unsigned)f2b(hv[2]) | ((unsigned)f2b(hv[3]) << 16);
            unsigned short* hd = hb16 + (size_t)((t + 1) & 1) * (BATCH * HID) +
                                 (size_t)blane * HID + c0col;
            LLC_STORE2(hd, pk);
            // out (cached path, coalesced float4)
            float4 o4 = make_float4(hv[0], hv[1], hv[2], hv[3]);
            *(float4*)(out + ((size_t)t * BATCH + blane) * HID + c0col) = o4;
            if (t == T_STEPS - 1) {
                *(float4*)(out + (size_t)T_STEPS * BATCH * HID +
                           (size_t)blane * HID + c0col) = o4;
                float4 c4 = make_float4(cst[0], cst[1], cst[2], cst[3]);
                *(float4*)(out + (size_t)T_STEPS * BATCH * HID + (size_t)BATCH * HID +
                           (size_t)blane * HID + c0col) = c4;
            }
            asm volatile("s_waitcnt vmcnt(0)" ::: "memory");
        }
        __syncthreads();
        if (tid == 0) {
            int tv = t + 1;
            int* tp = tags + (bj << 4);
            LLC_STORE1(tp, tv);
        }
    }
}

// ============================================================================
// Fallback (R4/R5 proven, fp32 mailbox + counter barrier): ws too small
// ============================================================================
__global__ __launch_bounds__(NTHR, 1) void lstm_persist_full(
    const float* __restrict__ x, const float* __restrict__ Wih,
    const float* __restrict__ Whh,
    const float* __restrict__ bih, const float* __restrict__ bhh,
    float* __restrict__ out, float* hbuf, int* barr)
{
    __shared__ float Wl[8][WSTRIDE_F];
    __shared__ float hl[HID][HSTRIDE];
    __shared__ float part[NKS][8][33];
    __shared__ float bias[8];
    __shared__ float cst[2 * BATCH];

    const int tid = threadIdx.x;
    const int bj  = blockIdx.x;
    const int r   = tid & 7;
    const int bg  = (tid >> 3) & 7;
    const int ks  = tid >> 6;
    const int bg4 = bg * 4;
    const int k0  = ks * 16;

    for (int i = tid; i < 8 * 256; i += NTHR) {
        int row = i >> 8, qq = i & 255;
        int R = ((row >> 1) << 9) + (bj << 1) + (row & 1);
        float4 v = (qq < 128) ? ((const float4*)(Wih + (size_t)R * DIM))[qq]
                              : ((const float4*)(Whh + (size_t)R * HID))[qq - 128];
        *(float4*)&Wl[row][qq * 4] = v;
    }
    if (tid < 8) {
        int R = ((tid >> 1) << 9) + (bj << 1) + (tid & 1);
        bias[tid] = bih[R] + bhh[R];
    }
    if (tid < 2 * BATCH) cst[tid] = 0.f;
    __syncthreads();

    const float4* __restrict__ wrow = (const float4*)&Wl[r][0];
    int* garr = barr;
    int* gctr = barr + 8 * 32;
    int* rel  = barr + 8 * 32 + 32;

    for (int t = 0; t < T_STEPS; ++t) {
        float4 A0 = {0,0,0,0}, A1 = {0,0,0,0}, A2 = {0,0,0,0}, A3 = {0,0,0,0};
        {
            const float* xb = x + ((size_t)t * BATCH + bg4) * DIM;
            const float4* v0 = (const float4*)xb;
            const float4* v1 = (const float4*)(xb + DIM);
            const float4* v2 = (const float4*)(xb + 2 * DIM);
            const float4* v3 = (const float4*)(xb + 3 * DIM);
#pragma unroll 4
            for (int k = 0; k < 16; ++k) {
                float4 w = wrow[k0 + k];
                float4 p0 = v0[k0 + k], p1 = v1[k0 + k], p2 = v2[k0 + k], p3 = v3[k0 + k];
                FMA4(A0, w, p0); FMA4(A1, w, p1); FMA4(A2, w, p2); FMA4(A3, w, p3);
            }
        }
        if (tid == 0) {
            while (__hip_atomic_load(rel, __ATOMIC_RELAXED, __HIP_MEMORY_SCOPE_AGENT) < t)
                __builtin_amdgcn_s_sleep(1);
        }
        __syncthreads();
        {
            const float* hsrc = hbuf + (size_t)(t & 1) * (HID * BATCH) + (tid << 2);
            float4 v0, v1, v2, v3, v4, v5, v6, v7;
            LLC_LOAD4(v0, hsrc);
            LLC_LOAD4(v1, hsrc + 2048);
            LLC_LOAD4(v2, hsrc + 4096);
            LLC_LOAD4(v3, hsrc + 6144);
            LLC_LOAD4(v4, hsrc + 8192);
            LLC_LOAD4(v5, hsrc + 10240);
            LLC_LOAD4(v6, hsrc + 12288);
            LLC_LOAD4(v7, hsrc + 14336);
            asm volatile("s_waitcnt vmcnt(0)" ::: "memory");
            __builtin_amdgcn_sched_barrier(0);
            float* wp = &hl[tid >> 3][(tid & 7) << 2];
            *(float4*)(wp + 0 * 64 * HSTRIDE) = v0;
            *(float4*)(wp + 1 * 64 * HSTRIDE) = v1;
            *(float4*)(wp + 2 * 64 * HSTRIDE) = v2;
            *(float4*)(wp + 3 * 64 * HSTRIDE) = v3;
            *(float4*)(wp + 4 * 64 * HSTRIDE) = v4;
            *(float4*)(wp + 5 * 64 * HSTRIDE) = v5;
            *(float4*)(wp + 6 * 64 * HSTRIDE) = v6;
            *(float4*)(wp + 7 * 64 * HSTRIDE) = v7;
        }
        __syncthreads();
        float4 H = {0,0,0,0};
#pragma unroll 4
        for (int kq = 0; kq < 16; ++kq) {
            int K = (ks << 6) + (kq << 2);
            float4 w4 = *(const float4*)&Wl[r][512 + K];
            float4 h0 = *(const float4*)&hl[K + 0][bg4];
            float4 h1 = *(const float4*)&hl[K + 1][bg4];
            float4 h2 = *(const float4*)&hl[K + 2][bg4];
            float4 h3 = *(const float4*)&hl[K + 3][bg4];
            FMAS(H, w4.x, h0); FMAS(H, w4.y, h1); FMAS(H, w4.z, h2); FMAS(H, w4.w, h3);
        }
        part[ks][r][bg4 + 0] = hsum4(A0) + H.x;
        part[ks][r][bg4 + 1] = hsum4(A1) + H.y;
        part[ks][r][bg4 + 2] = hsum4(A2) + H.z;
        part[ks][r][bg4 + 3] = hsum4(A3) + H.w;
        __syncthreads();
        float hval = 0.f, cval = 0.f;
        if (tid < 2 * BATCH) {
            int jj = tid & 1, b = tid >> 1;
            float gi = bias[0 + jj], gf = bias[2 + jj], gg = bias[4 + jj], go = bias[6 + jj];
#pragma unroll
            for (int kk = 0; kk < NKS; ++kk) {
                gi += part[kk][0 + jj][b];
                gf += part[kk][2 + jj][b];
                gg += part[kk][4 + jj][b];
                go += part[kk][6 + jj][b];
            }
            float ig = sigm(gi), fg = sigm(gf), og = sigm(go);
            float g  = tanhf(gg);
            float c  = fg * cst[tid] + ig * g;
            cst[tid] = c;
            float h  = og * tanhf(c);
            hval = h; cval = c;
            int j = (bj << 1) + jj;
            __hip_atomic_store(hbuf + (size_t)((t + 1) & 1) * (HID * BATCH) + (size_t)j * BATCH + b,
                               h, __ATOMIC_RELAXED, __HIP_MEMORY_SCOPE_AGENT);
        }
        asm volatile("s_waitcnt vmcnt(0)" ::: "memory");
        if (tid == 0) {
            int grp = bj & 7;
            int old = __hip_atomic_fetch_add(&garr[grp * 32], 1, __ATOMIC_RELAXED,
                                             __HIP_MEMORY_SCOPE_AGENT);
            if (old == (t + 1) * 32 - 1) {
                int o2 = __hip_atomic_fetch_add(gctr, 1, __ATOMIC_RELAXED,
                                                __HIP_MEMORY_SCOPE_AGENT);
                if (o2 == (t + 1) * 8 - 1) {
                    __hip_atomic_fetch_add(rel, 1, __ATOMIC_RELAXED,
                                           __HIP_MEMORY_SCOPE_AGENT);
                }
            }
        }
        if (tid < 2 * BATCH) {
            int jj = tid & 1, b = tid >> 1;
            int j = (bj << 1) + jj;
            out[((size_t)t * BATCH + b) * HID + j] = hval;
            if (t == T_STEPS - 1) {
                out[(size_t)T_STEPS * BATCH * HID + (size_t)b * HID + j] = hval;
                out[(size_t)T_STEPS * BATCH * HID + (size_t)BATCH * HID + (size_t)b * HID + j] = cval;
            }
        }
    }
}

extern "C" void kernel_launch(void* const* d_in, const int* in_sizes, int n_in,
                              void* d_out, int out_size, void* d_ws, size_t ws_size,
                              hipStream_t stream) {
    (void)in_sizes; (void)n_in; (void)out_size;
    const float* x   = (const float*)d_in[0];
    const float* Wih = (const float*)d_in[1];
    const float* Whh = (const float*)d_in[2];
    const float* bih = (const float*)d_in[3];
    const float* bhh = (const float*)d_in[4];
    float* outp = (float*)d_out;
    int*   barr = (int*)((char*)d_ws + BARR_OFF);

    // zero mailbox region + tags every call (deterministic across replays)
    hipMemsetAsync(d_ws, 0, BARR_OFF + 4096, stream);

    const size_t need = (size_t)XP_OFF + XP_BYTES;
    if (ws_size >= need) {
        unsigned short* hb16 = (unsigned short*)d_ws;
        unsigned short* xpb  = (unsigned short*)((char*)d_ws + XP_OFF);
        xproj_gemm<<<(MROWS / 64) * (NCOLS / 64), 256, 0, stream>>>(x, Wih, xpb);
        lstm_mfma<<<NBK, NTHR, 0, stream>>>(xpb, Whh, bih, bhh, outp, hb16, barr);
    } else {
        float* hbuf = (float*)d_ws;
        lstm_persist_full<<<NB_FALLBACK, NTHR, 0, stream>>>(x, Wih, Whh, bih, bhh, outp, hbuf, barr);
    }
}

// Round 12
// 13345.087 us; speedup vs baseline: 1.0076x; 1.0076x over previous
//
#include <hip/hip_runtime.h>

#define T_STEPS 2048
#define BATCH   32
#define DIM     512
#define HID     512
#define NBK     16          // recurrence blocks; NBK * 32 cols == HID
#define NB_FALLBACK 256
#define NTHR    512
#define NKS     8
#define WSTRIDE_F 1028      // fallback fused [Wih|Whh] rows
#define HSTRIDE 36
#define MROWS   (T_STEPS * BATCH)   // 65536
#define NCOLS   (4 * HID)           // 2048

// ws layout: [0,128K) mailbox region (MFMA path: first 64K bf16 [2][b][col];
//            fallback: fp32) | [128K,132K) tags/barrier | [132K,..) x_proj
#define BARR_OFF     (128 * 1024)
#define XP_OFF       (132 * 1024)
#define XP_BYTES     ((size_t)MROWS * NCOLS * 2)

#define FMA4(A, W, P) do { A.x = fmaf(W.x, P.x, A.x); A.y = fmaf(W.y, P.y, A.y); \
                           A.z = fmaf(W.z, P.z, A.z); A.w = fmaf(W.w, P.w, A.w); } while (0)
#define FMAS(A, s, P) do { A.x = fmaf(s, P.x, A.x); A.y = fmaf(s, P.y, A.y); \
                           A.z = fmaf(s, P.z, A.z); A.w = fmaf(s, P.w, A.w); } while (0)

#define LLC_LOAD4(dst, p) \
    asm volatile("global_load_dwordx4 %0, %1, off sc0 sc1" : "=v"(dst) : "v"(p) : "memory")
#define LLC_LOAD4_OFF(dst, p, imm) \
    asm volatile("global_load_dwordx4 %0, %1, off offset:" #imm " sc0 sc1" \
                 : "=v"(dst) : "v"(p) : "memory")
#define LLC_LOADD(dst, p) \
    asm volatile("global_load_dword %0, %1, off sc0 sc1" : "=v"(dst) : "v"(p) : "memory")
#define LLC_STORE1(p, v) \
    asm volatile("global_store_dword %0, %1, off sc0 sc1" :: "v"(p), "v"(v) : "memory")
#define LLC_STORE2(p, v) \
    asm volatile("global_store_dwordx2 %0, %1, off sc0 sc1" :: "v"(p), "v"(v) : "memory")

#define B2F(s) __uint_as_float(((unsigned)(unsigned short)(s)) << 16)

__device__ __forceinline__ float hsum4(float4 a) { return (a.x + a.y) + (a.z + a.w); }
__device__ __forceinline__ float sigm(float x) { return 1.f / (1.f + __expf(-x)); }

__device__ __forceinline__ unsigned short f2b(float f) {  // fp32 -> bf16 RNE
    unsigned u = __float_as_uint(f);
    return (unsigned short)((u + 0x7fffu + ((u >> 16) & 1u)) >> 16);
}

using s8v = __attribute__((ext_vector_type(8))) short;
using f4v = __attribute__((ext_vector_type(4))) float;

// ============================================================================
// Kernel 1: x_proj[M=T*B][N=4H] = x[M][512] * Wih^T  (proven R5-R10)
// ============================================================================
__global__ __launch_bounds__(256, 2) void xproj_gemm(
    const float* __restrict__ x, const float* __restrict__ Wih,
    unsigned short* __restrict__ xp)
{
    __shared__ unsigned short As[64][40];
    __shared__ unsigned short Bs[64][40];
    const int tid  = threadIdx.x;
    const int mi   = blockIdx.x >> 5;
    const int ni   = blockIdx.x & 31;
    const int lane = tid & 63;
    const int wv   = tid >> 6;
    const int wr   = (wv >> 1) * 32, wc = (wv & 1) * 32;
    const int r0   = lane & 15, kb = (lane >> 4) * 8;

    f4v acc00 = {0,0,0,0}, acc01 = {0,0,0,0}, acc10 = {0,0,0,0}, acc11 = {0,0,0,0};

    for (int ko = 0; ko < 512; ko += 32) {
        __syncthreads();
#pragma unroll
        for (int i = tid; i < 512; i += 256) {
            int row = i >> 3, kq = i & 7;
            float4 va = *(const float4*)(x   + (size_t)(mi * 64 + row) * 512 + ko + kq * 4);
            float4 vb = *(const float4*)(Wih + (size_t)(ni * 64 + row) * 512 + ko + kq * 4);
            uint2 ua = make_uint2((unsigned)f2b(va.x) | ((unsigned)f2b(va.y) << 16),
                                  (unsigned)f2b(va.z) | ((unsigned)f2b(va.w) << 16));
            uint2 ub = make_uint2((unsigned)f2b(vb.x) | ((unsigned)f2b(vb.y) << 16),
                                  (unsigned)f2b(vb.z) | ((unsigned)f2b(vb.w) << 16));
            *(uint2*)&As[row][kq * 4] = ua;
            *(uint2*)&Bs[row][kq * 4] = ub;
        }
        __syncthreads();
        s8v a0 = *(const s8v*)&As[wr      + r0][kb];
        s8v a1 = *(const s8v*)&As[wr + 16 + r0][kb];
        s8v b0 = *(const s8v*)&Bs[wc      + r0][kb];
        s8v b1 = *(const s8v*)&Bs[wc + 16 + r0][kb];
        acc00 = __builtin_amdgcn_mfma_f32_16x16x32_bf16(a0, b0, acc00, 0, 0, 0);
        acc01 = __builtin_amdgcn_mfma_f32_16x16x32_bf16(a0, b1, acc01, 0, 0, 0);
        acc10 = __builtin_amdgcn_mfma_f32_16x16x32_bf16(a1, b0, acc10, 0, 0, 0);
        acc11 = __builtin_amdgcn_mfma_f32_16x16x32_bf16(a1, b1, acc11, 0, 0, 0);
    }
    const int rb = (lane >> 4) * 4, cb = lane & 15;
#pragma unroll
    for (int j = 0; j < 4; ++j) {
        size_t rA = (size_t)(mi * 64 + wr + rb + j) * NCOLS + (ni * 64 + wc + cb);
        size_t rB = (size_t)(mi * 64 + wr + 16 + rb + j) * NCOLS + (ni * 64 + wc + cb);
        xp[rA]        = f2b(acc00[j]);
        xp[rA + 16]   = f2b(acc01[j]);
        xp[rB]        = f2b(acc10[j]);
        xp[rB + 16]   = f2b(acc11[j]);
    }
}

// ============================================================================
// Kernel 2: 16-block MFMA recurrence (R10 structure, un-spilled).
// __launch_bounds__(512,1): natural ~230 VGPR so aw[4][8] stays in registers.
// out stores moved AFTER the tag store (off the serial chain).
// ============================================================================
__global__ __launch_bounds__(NTHR, 1) void lstm_mfma(
    const unsigned short* __restrict__ xp,   // [T*B][4H] bf16
    const float* __restrict__ Whh,
    const float* __restrict__ bih, const float* __restrict__ bhh,
    float* __restrict__ out,
    unsigned short* hb16, int* tags)         // hb16[2][B][H] bf16; tags[NBK*16]
{
    __shared__ float comb[4][16][66];        // [quadrant][gate*4+reg][lane] 16.9 KB

    const int tid   = threadIdx.x;
    const int bj    = blockIdx.x;            // 0..15
    const int lane  = tid & 63;
    const int wv    = tid >> 6;
    const int q     = wv & 3;                // quadrant
    const int ks2   = wv >> 2;               // K half (0/1)
    const int cg    = q >> 1, ng = q & 1;
    const int C0    = bj * 32;               // 16 * 32 == 512 == HID
    const int r0    = lane & 15;
    const int l16   = lane >> 4;
    const int blane = ng * 16 + r0;          // batch index (D: N = lane&15)
    const int c0col = C0 + cg * 16 + l16 * 4; // lane's 4 cols (D: M = (lane>>4)*4+reg)

    // ---- one-time: Whh -> bf16 A-frags (4 gates x 8 K-chunks of this K-half) ----
    s8v aw[4][8];
#pragma unroll
    for (int g = 0; g < 4; ++g) {
#pragma unroll
        for (int kc = 0; kc < 8; ++kc) {
            int R = g * 512 + C0 + cg * 16 + r0;
            int k = ks2 * 256 + kc * 32 + l16 * 8;
            const float* wp = Whh + (size_t)R * 512 + k;
            float4 a = *(const float4*)wp;
            float4 b = *(const float4*)(wp + 4);
            s8v f;
            f[0] = (short)f2b(a.x); f[1] = (short)f2b(a.y);
            f[2] = (short)f2b(a.z); f[3] = (short)f2b(a.w);
            f[4] = (short)f2b(b.x); f[5] = (short)f2b(b.y);
            f[6] = (short)f2b(b.z); f[7] = (short)f2b(b.w);
            aw[g][kc] = f;
        }
    }
    float bs[4][4];
    float cst[4] = {0.f, 0.f, 0.f, 0.f};
    if (ks2 == 0) {
#pragma unroll
        for (int g = 0; g < 4; ++g)
#pragma unroll
            for (int r = 0; r < 4; ++r) {
                int c = g * 512 + c0col + r;
                bs[g][r] = bih[c] + bhh[c];
            }
    }

    for (int t = 0; t < T_STEPS; ++t) {
        // ---- xp prefetch (primary waves), issued before poll ----
        short4 ux0, ux1, ux2, ux3;
        if (ks2 == 0) {
            const unsigned short* xpp = xp + ((size_t)t * BATCH + blane) * NCOLS + c0col;
            ux0 = *(const short4*)(xpp);
            ux1 = *(const short4*)(xpp + 512);
            ux2 = *(const short4*)(xpp + 1024);
            ux3 = *(const short4*)(xpp + 1536);
        }

        // ---- wave-0-only poll over NBK tag lines, then barrier release ----
        if (tid < 64) {
            const int* tp = tags + ((lane & (NBK - 1)) << 4);
            while (true) {
                int tg;
                LLC_LOADD(tg, tp);
                asm volatile("s_waitcnt vmcnt(0)" ::: "memory");
                if (__all(tg >= t)) break;
                __builtin_amdgcn_s_sleep(1);
            }
        }
        __syncthreads();

        // ---- B-frags: h (bf16) DIRECT from LLC mailbox, 8 x 16B per lane ----
        uint4 bfr[8];
        {
            const unsigned short* hs = hb16 + (size_t)(t & 1) * (BATCH * HID) +
                                       (size_t)blane * HID + ks2 * 256 + l16 * 8;
            LLC_LOAD4_OFF(bfr[0], hs, 0);
            LLC_LOAD4_OFF(bfr[1], hs, 64);
            LLC_LOAD4_OFF(bfr[2], hs, 128);
            LLC_LOAD4_OFF(bfr[3], hs, 192);
            LLC_LOAD4_OFF(bfr[4], hs, 256);
            LLC_LOAD4_OFF(bfr[5], hs, 320);
            LLC_LOAD4_OFF(bfr[6], hs, 384);
            LLC_LOAD4_OFF(bfr[7], hs, 448);
            asm volatile("s_waitcnt vmcnt(0)" ::: "memory");
            __builtin_amdgcn_sched_barrier(0);
        }

        // ---- MFMA: 4 gates x 8 K-chunks (this wave's K-half) ----
        f4v acc0 = {0,0,0,0}, acc1 = {0,0,0,0}, acc2 = {0,0,0,0}, acc3 = {0,0,0,0};
#pragma unroll
        for (int kc = 0; kc < 8; ++kc) {
            s8v bf = *(const s8v*)&bfr[kc];
            acc0 = __builtin_amdgcn_mfma_f32_16x16x32_bf16(aw[0][kc], bf, acc0, 0, 0, 0);
            acc1 = __builtin_amdgcn_mfma_f32_16x16x32_bf16(aw[1][kc], bf, acc1, 0, 0, 0);
            acc2 = __builtin_amdgcn_mfma_f32_16x16x32_bf16(aw[2][kc], bf, acc2, 0, 0, 0);
            acc3 = __builtin_amdgcn_mfma_f32_16x16x32_bf16(aw[3][kc], bf, acc3, 0, 0, 0);
        }

        // ---- K-half exchange: scalar b32, lane-consecutive (conflict-free) ----
        if (ks2 == 1) {
#pragma unroll
            for (int j = 0; j < 4; ++j) {
                comb[q][0  + j][lane] = acc0[j];
                comb[q][4  + j][lane] = acc1[j];
                comb[q][8  + j][lane] = acc2[j];
                comb[q][12 + j][lane] = acc3[j];
            }
        }
        __syncthreads();

        // ---- gates (primary waves): per-lane, pure VALU; publish h only ----
        float hv[4];
        if (ks2 == 0) {
#pragma unroll
            for (int j = 0; j < 4; ++j) {
                float gi = acc0[j] + comb[q][0  + j][lane] + bs[0][j] + B2F(((short*)&ux0)[j]);
                float gf = acc1[j] + comb[q][4  + j][lane] + bs[1][j] + B2F(((short*)&ux1)[j]);
                float gg = acc2[j] + comb[q][8  + j][lane] + bs[2][j] + B2F(((short*)&ux2)[j]);
                float go = acc3[j] + comb[q][12 + j][lane] + bs[3][j] + B2F(((short*)&ux3)[j]);
                float ig = sigm(gi), fg = sigm(gf), og = sigm(go);
                float g  = tanhf(gg);
                float c  = fg * cst[j] + ig * g;
                cst[j] = c;
                hv[j] = og * tanhf(c);
            }
            uint2 pk;
            pk.x = (unsigned)f2b(hv[0]) | ((unsigned)f2b(hv[1]) << 16);
            pk.y = (unsigned)f2b(hv[2]) | ((unsigned)f2b(hv[3]) << 16);
            unsigned short* hd = hb16 + (size_t)((t + 1) & 1) * (BATCH * HID) +
                                 (size_t)blane * HID + c0col;
            LLC_STORE2(hd, pk);
        }

        // drain h publish, block-wide完成 guarantee, then tag immediately
        asm volatile("s_waitcnt vmcnt(0)" ::: "memory");
        __syncthreads();
        if (tid == 0) {
            int tv = t + 1;
            int* tp = tags + (bj << 4);
            LLC_STORE1(tp, tv);
        }

        // ---- out stores OFF the chain (after tag; cached path) ----
        if (ks2 == 0) {
            float4 o4 = make_float4(hv[0], hv[1], hv[2], hv[3]);
            *(float4*)(out + ((size_t)t * BATCH + blane) * HID + c0col) = o4;
            if (t == T_STEPS - 1) {
                *(float4*)(out + (size_t)T_STEPS * BATCH * HID +
                           (size_t)blane * HID + c0col) = o4;
                float4 c4 = make_float4(cst[0], cst[1], cst[2], cst[3]);
                *(float4*)(out + (size_t)T_STEPS * BATCH * HID + (size_t)BATCH * HID +
                           (size_t)blane * HID + c0col) = c4;
            }
        }
    }
}

// ============================================================================
// Fallback (R4/R5 proven, fp32 mailbox + counter barrier): ws too small
// ============================================================================
__global__ __launch_bounds__(NTHR, 1) void lstm_persist_full(
    const float* __restrict__ x, const float* __restrict__ Wih,
    const float* __restrict__ Whh,
    const float* __restrict__ bih, const float* __restrict__ bhh,
    float* __restrict__ out, float* hbuf, int* barr)
{
    __shared__ float Wl[8][WSTRIDE_F];
    __shared__ float hl[HID][HSTRIDE];
    __shared__ float part[NKS][8][33];
    __shared__ float bias[8];
    __shared__ float cst[2 * BATCH];

    const int tid = threadIdx.x;
    const int bj  = blockIdx.x;
    const int r   = tid & 7;
    const int bg  = (tid >> 3) & 7;
    const int ks  = tid >> 6;
    const int bg4 = bg * 4;
    const int k0  = ks * 16;

    for (int i = tid; i < 8 * 256; i += NTHR) {
        int row = i >> 8, qq = i & 255;
        int R = ((row >> 1) << 9) + (bj << 1) + (row & 1);
        float4 v = (qq < 128) ? ((const float4*)(Wih + (size_t)R * DIM))[qq]
                              : ((const float4*)(Whh + (size_t)R * HID))[qq - 128];
        *(float4*)&Wl[row][qq * 4] = v;
    }
    if (tid < 8) {
        int R = ((tid >> 1) << 9) + (bj << 1) + (tid & 1);
        bias[tid] = bih[R] + bhh[R];
    }
    if (tid < 2 * BATCH) cst[tid] = 0.f;
    __syncthreads();

    const float4* __restrict__ wrow = (const float4*)&Wl[r][0];
    int* garr = barr;
    int* gctr = barr + 8 * 32;
    int* rel  = barr + 8 * 32 + 32;

    for (int t = 0; t < T_STEPS; ++t) {
        float4 A0 = {0,0,0,0}, A1 = {0,0,0,0}, A2 = {0,0,0,0}, A3 = {0,0,0,0};
        {
            const float* xb = x + ((size_t)t * BATCH + bg4) * DIM;
            const float4* v0 = (const float4*)xb;
            const float4* v1 = (const float4*)(xb + DIM);
            const float4* v2 = (const float4*)(xb + 2 * DIM);
            const float4* v3 = (const float4*)(xb + 3 * DIM);
#pragma unroll 4
            for (int k = 0; k < 16; ++k) {
                float4 w = wrow[k0 + k];
                float4 p0 = v0[k0 + k], p1 = v1[k0 + k], p2 = v2[k0 + k], p3 = v3[k0 + k];
                FMA4(A0, w, p0); FMA4(A1, w, p1); FMA4(A2, w, p2); FMA4(A3, w, p3);
            }
        }
        if (tid == 0) {
            while (__hip_atomic_load(rel, __ATOMIC_RELAXED, __HIP_MEMORY_SCOPE_AGENT) < t)
                __builtin_amdgcn_s_sleep(1);
        }
        __syncthreads();
        {
            const float* hsrc = hbuf + (size_t)(t & 1) * (HID * BATCH) + (tid << 2);
            float4 v0, v1, v2, v3, v4, v5, v6, v7;
            LLC_LOAD4(v0, hsrc);
            LLC_LOAD4(v1, hsrc + 2048);
            LLC_LOAD4(v2, hsrc + 4096);
            LLC_LOAD4(v3, hsrc + 6144);
            LLC_LOAD4(v4, hsrc + 8192);
            LLC_LOAD4(v5, hsrc + 10240);
            LLC_LOAD4(v6, hsrc + 12288);
            LLC_LOAD4(v7, hsrc + 14336);
            asm volatile("s_waitcnt vmcnt(0)" ::: "memory");
            __builtin_amdgcn_sched_barrier(0);
            float* wp = &hl[tid >> 3][(tid & 7) << 2];
            *(float4*)(wp + 0 * 64 * HSTRIDE) = v0;
            *(float4*)(wp + 1 * 64 * HSTRIDE) = v1;
            *(float4*)(wp + 2 * 64 * HSTRIDE) = v2;
            *(float4*)(wp + 3 * 64 * HSTRIDE) = v3;
            *(float4*)(wp + 4 * 64 * HSTRIDE) = v4;
            *(float4*)(wp + 5 * 64 * HSTRIDE) = v5;
            *(float4*)(wp + 6 * 64 * HSTRIDE) = v6;
            *(float4*)(wp + 7 * 64 * HSTRIDE) = v7;
        }
        __syncthreads();
        float4 H = {0,0,0,0};
#pragma unroll 4
        for (int kq = 0; kq < 16; ++kq) {
            int K = (ks << 6) + (kq << 2);
            float4 w4 = *(const float4*)&Wl[r][512 + K];
            float4 h0 = *(const float4*)&hl[K + 0][bg4];
            float4 h1 = *(const float4*)&hl[K + 1][bg4];
            float4 h2 = *(const float4*)&hl[K + 2][bg4];
            float4 h3 = *(const float4*)&hl[K + 3][bg4];
            FMAS(H, w4.x, h0); FMAS(H, w4.y, h1); FMAS(H, w4.z, h2); FMAS(H, w4.w, h3);
        }
        part[ks][r][bg4 + 0] = hsum4(A0) + H.x;
        part[ks][r][bg4 + 1] = hsum4(A1) + H.y;
        part[ks][r][bg4 + 2] = hsum4(A2) + H.z;
        part[ks][r][bg4 + 3] = hsum4(A3) + H.w;
        __syncthreads();
        float hval = 0.f, cval = 0.f;
        if (tid < 2 * BATCH) {
            int jj = tid & 1, b = tid >> 1;
            float gi = bias[0 + jj], gf = bias[2 + jj], gg = bias[4 + jj], go = bias[6 + jj];
#pragma unroll
            for (int kk = 0; kk < NKS; ++kk) {
                gi += part[kk][0 + jj][b];
                gf += part[kk][2 + jj][b];
                gg += part[kk][4 + jj][b];
                go += part[kk][6 + jj][b];
            }
            float ig = sigm(gi), fg = sigm(gf), og = sigm(go);
            float g  = tanhf(gg);
            float c  = fg * cst[tid] + ig * g;
            cst[tid] = c;
            float h  = og * tanhf(c);
            hval = h; cval = c;
            int j = (bj << 1) + jj;
            __hip_atomic_store(hbuf + (size_t)((t + 1) & 1) * (HID * BATCH) + (size_t)j * BATCH + b,
                               h, __ATOMIC_RELAXED, __HIP_MEMORY_SCOPE_AGENT);
        }
        asm volatile("s_waitcnt vmcnt(0)" ::: "memory");
        if (tid == 0) {
            int grp = bj & 7;
            int old = __hip_atomic_fetch_add(&garr[grp * 32], 1, __ATOMIC_RELAXED,
                                             __HIP_MEMORY_SCOPE_AGENT);
            if (old == (t + 1) * 32 - 1) {
                int o2 = __hip_atomic_fetch_add(gctr, 1, __ATOMIC_RELAXED,
                                                __HIP_MEMORY_SCOPE_AGENT);
                if (o2 == (t + 1) * 8 - 1) {
                    __hip_atomic_fetch_add(rel, 1, __ATOMIC_RELAXED,
                                           __HIP_MEMORY_SCOPE_AGENT);
                }
            }
        }
        if (tid < 2 * BATCH) {
            int jj = tid & 1, b = tid >> 1;
            int j = (bj << 1) + jj;
            out[((size_t)t * BATCH + b) * HID + j] = hval;
            if (t == T_STEPS - 1) {
                out[(size_t)T_STEPS * BATCH * HID + (size_t)b * HID + j] = hval;
                out[(size_t)T_STEPS * BATCH * HID + (size_t)BATCH * HID + (size_t)b * HID + j] = cval;
            }
        }
    }
}

extern "C" void kernel_launch(void* const* d_in, const int* in_sizes, int n_in,
                              void* d_out, int out_size, void* d_ws, size_t ws_size,
                              hipStream_t stream) {
    (void)in_sizes; (void)n_in; (void)out_size;
    const float* x   = (const float*)d_in[0];
    const float* Wih = (const float*)d_in[1];
    const float* Whh = (const float*)d_in[2];
    const float* bih = (const float*)d_in[3];
    const float* bhh = (const float*)d_in[4];
    float* outp = (float*)d_out;
    int*   barr = (int*)((char*)d_ws + BARR_OFF);

    // zero mailbox region + tags every call (deterministic across replays)
    hipMemsetAsync(d_ws, 0, BARR_OFF + 4096, stream);

    const size_t need = (size_t)XP_OFF + XP_BYTES;
    if (ws_size >= need) {
        unsigned short* hb16 = (unsigned short*)d_ws;
        unsigned short* xpb  = (unsigned short*)((char*)d_ws + XP_OFF);
        xproj_gemm<<<(MROWS / 64) * (NCOLS / 64), 256, 0, stream>>>(x, Wih, xpb);
        lstm_mfma<<<NBK, NTHR, 0, stream>>>(xpb, Whh, bih, bhh, outp, hb16, barr);
    } else {
        float* hbuf = (float*)d_ws;
        lstm_persist_full<<<NB_FALLBACK, NTHR, 0, stream>>>(x, Wih, Whh, bih, bhh, outp, hbuf, barr);
    }
}

// Round 13
// 9451.281 us; speedup vs baseline: 1.4227x; 1.4120x over previous
//
#include <hip/hip_runtime.h>

#define T_STEPS 2048
#define BATCH   32
#define DIM     512
#define HID     512
#define NB      256
#define JB      2
#define NTHR    512
#define NKS     8
#define WSTRIDE   516   // Whh-only rows: 512+4 pad
#define WSTRIDE_F 1028  // fallback fused [Wih|Whh] rows
#define HSTRIDE 36
#define MROWS   (T_STEPS * BATCH)   // 65536
#define NCOLS   (4 * HID)           // 2048

#define HBUF_BYTES (2 * HID * BATCH * 4)
#define BARR_BYTES 4096
#define XP_BYTES   ((size_t)MROWS * NCOLS * 2)

#define FMA4(A, W, P) do { A.x = fmaf(W.x, P.x, A.x); A.y = fmaf(W.y, P.y, A.y); \
                           A.z = fmaf(W.z, P.z, A.z); A.w = fmaf(W.w, P.w, A.w); } while (0)
#define FMAS(A, s, P) do { A.x = fmaf(s, P.x, A.x); A.y = fmaf(s, P.y, A.y); \
                           A.z = fmaf(s, P.z, A.z); A.w = fmaf(s, P.w, A.w); } while (0)

#define LLC_LOAD4(dst, p) \
    asm volatile("global_load_dwordx4 %0, %1, off sc0 sc1" : "=v"(dst) : "v"(p) : "memory")

__device__ __forceinline__ float hsum4(float4 a) { return (a.x + a.y) + (a.z + a.w); }

__device__ __forceinline__ unsigned short f2b(float f) {  // fp32 -> bf16 RNE
    unsigned u = __float_as_uint(f);
    return (unsigned short)((u + 0x7fffu + ((u >> 16) & 1u)) >> 16);
}

// ============================================================================
// Kernel 1: x_proj[M=T*B][N=4H] = x[M][512] * Wih^T  (bf16 in, fp32 acc, bf16 out)
// 64x64 tile, 4 waves of 32x32, mfma_f32_16x16x32_bf16, BK=32.
// ============================================================================
using s8v = __attribute__((ext_vector_type(8))) short;
using f4v = __attribute__((ext_vector_type(4))) float;

__global__ __launch_bounds__(256, 2) void xproj_gemm(
    const float* __restrict__ x, const float* __restrict__ Wih,
    unsigned short* __restrict__ xp)
{
    __shared__ unsigned short As[64][40];   // pad 40: frag reads 2-way only
    __shared__ unsigned short Bs[64][40];
    const int tid  = threadIdx.x;
    const int mi   = blockIdx.x >> 5;       // 32 consecutive blocks share mi -> A L2-hot
    const int ni   = blockIdx.x & 31;
    const int lane = tid & 63;
    const int wv   = tid >> 6;
    const int wr   = (wv >> 1) * 32, wc = (wv & 1) * 32;
    const int r0   = lane & 15, kb = (lane >> 4) * 8;

    f4v acc00 = {0,0,0,0}, acc01 = {0,0,0,0}, acc10 = {0,0,0,0}, acc11 = {0,0,0,0};

    for (int ko = 0; ko < 512; ko += 32) {
        __syncthreads();
#pragma unroll
        for (int i = tid; i < 512; i += 256) {
            int row = i >> 3, kq = i & 7;
            float4 va = *(const float4*)(x   + (size_t)(mi * 64 + row) * 512 + ko + kq * 4);
            float4 vb = *(const float4*)(Wih + (size_t)(ni * 64 + row) * 512 + ko + kq * 4);
            uint2 ua = make_uint2((unsigned)f2b(va.x) | ((unsigned)f2b(va.y) << 16),
                                  (unsigned)f2b(va.z) | ((unsigned)f2b(va.w) << 16));
            uint2 ub = make_uint2((unsigned)f2b(vb.x) | ((unsigned)f2b(vb.y) << 16),
                                  (unsigned)f2b(vb.z) | ((unsigned)f2b(vb.w) << 16));
            *(uint2*)&As[row][kq * 4] = ua;
            *(uint2*)&Bs[row][kq * 4] = ub;
        }
        __syncthreads();
        s8v a0 = *(const s8v*)&As[wr      + r0][kb];
        s8v a1 = *(const s8v*)&As[wr + 16 + r0][kb];
        s8v b0 = *(const s8v*)&Bs[wc      + r0][kb];
        s8v b1 = *(const s8v*)&Bs[wc + 16 + r0][kb];
        acc00 = __builtin_amdgcn_mfma_f32_16x16x32_bf16(a0, b0, acc00, 0, 0, 0);
        acc01 = __builtin_amdgcn_mfma_f32_16x16x32_bf16(a0, b1, acc01, 0, 0, 0);
        acc10 = __builtin_amdgcn_mfma_f32_16x16x32_bf16(a1, b0, acc10, 0, 0, 0);
        acc11 = __builtin_amdgcn_mfma_f32_16x16x32_bf16(a1, b1, acc11, 0, 0, 0);
    }
    // C/D layout (m89): col = lane&15, row = (lane>>4)*4 + reg
    const int rb = (lane >> 4) * 4, cb = lane & 15;
#pragma unroll
    for (int j = 0; j < 4; ++j) {
        size_t rA = (size_t)(mi * 64 + wr + rb + j) * NCOLS + (ni * 64 + wc + cb);
        size_t rB = (size_t)(mi * 64 + wr + 16 + rb + j) * NCOLS + (ni * 64 + wc + cb);
        xp[rA]        = f2b(acc00[j]);
        xp[rA + 16]   = f2b(acc01[j]);
        xp[rB]        = f2b(acc10[j]);
        xp[rB + 16]   = f2b(acc11[j]);
    }
}

// ============================================================================
// Kernel 2: persistent recurrence consuming precomputed x_proj (R5, 9.52 ms)
// ============================================================================
__global__ __launch_bounds__(NTHR, 1) void lstm_persist_xp(
    const unsigned short* __restrict__ xp,   // [M][4H] bf16
    const float* __restrict__ Whh,
    const float* __restrict__ bih, const float* __restrict__ bhh,
    float* __restrict__ out,
    float* hbuf, int* barr)                  // barr: garr[8*32] monotone counters
{
    __shared__ float Wl[8][WSTRIDE];      // Whh rows only (16.5 KB)
    __shared__ float hl[HID][HSTRIDE];    // h_{t-1} as [k][b] (73.7 KB)
    __shared__ float part[NKS][8][33];
    __shared__ float bias[8];
    __shared__ float cst[JB * BATCH];

    const int tid = threadIdx.x;
    const int bj  = blockIdx.x;
    const int r   = tid & 7;
    const int bg  = (tid >> 3) & 7;
    const int ks  = tid >> 6;
    const int bg4 = bg * 4;

    for (int i = tid; i < 8 * 128; i += NTHR) {
        int row = i >> 7, q = i & 127;
        int R = ((row >> 1) << 9) + (bj << 1) + (row & 1);
        *(float4*)&Wl[row][q * 4] = ((const float4*)(Whh + (size_t)R * HID))[q];
    }
    if (tid < 8) {
        int R = ((tid >> 1) << 9) + (bj << 1) + (tid & 1);
        bias[tid] = bih[R] + bhh[R];
    }
    if (tid < JB * BATCH) cst[tid] = 0.f;
    __syncthreads();

    int* garr = barr;
    const int jj = tid & 1, bb = tid >> 1;           // gate-thread coords (tid<64)
    const size_t xbase0 = (size_t)bb * NCOLS + (bj << 1) + jj;

    for (int t = 0; t < T_STEPS; ++t) {
        // ---- prefetch x_proj slice (normal cached loads; hidden under poll+stage) ----
        unsigned short u0 = 0, u1 = 0, u2 = 0, u3 = 0;
        if (tid < 64) {
            const unsigned short* p = xp + (size_t)t * BATCH * NCOLS + xbase0;
            u0 = p[0]; u1 = p[512]; u2 = p[1024]; u3 = p[1536];
        }

        // ---- flat poll: wave 0 lanes watch all 8 group counters ----
        if (tid < 64) {
            const int target = t * 32;
            const int* cp = &garr[(tid & 7) * 32];
            while (true) {
                int v = __hip_atomic_load(cp, __ATOMIC_RELAXED, __HIP_MEMORY_SCOPE_AGENT);
                if (__all(v >= target)) break;
                __builtin_amdgcn_s_sleep(1);
            }
        }
        __syncthreads();

        // ---- stage h: coalesced sc0sc1 16B loads, block-rotated -> hl[k][b] ----
        {
            const float* hsrc = hbuf + (size_t)(t & 1) * (HID * BATCH) + (tid << 2);
            float* wp = &hl[tid >> 3][(tid & 7) << 2];
            float4 vv[8];
#pragma unroll
            for (int it = 0; it < 8; ++it) {
                int p = (it + bj) & 7;
                LLC_LOAD4(vv[it], hsrc + p * 2048);
            }
            asm volatile("s_waitcnt vmcnt(0)" ::: "memory");
            __builtin_amdgcn_sched_barrier(0);
#pragma unroll
            for (int it = 0; it < 8; ++it) {
                int p = (it + bj) & 7;
                *(float4*)(wp + p * 64 * HSTRIDE) = vv[it];
            }
        }
        __syncthreads();

        // ---- h-GEMM from LDS ----
        float4 H = {0, 0, 0, 0};
#pragma unroll 4
        for (int kq = 0; kq < 16; ++kq) {
            int K = (ks << 6) + (kq << 2);
            float4 w4 = *(const float4*)&Wl[r][K];
            float4 h0 = *(const float4*)&hl[K + 0][bg4];
            float4 h1 = *(const float4*)&hl[K + 1][bg4];
            float4 h2 = *(const float4*)&hl[K + 2][bg4];
            float4 h3 = *(const float4*)&hl[K + 3][bg4];
            FMAS(H, w4.x, h0); FMAS(H, w4.y, h1); FMAS(H, w4.z, h2); FMAS(H, w4.w, h3);
        }
        part[ks][r][bg4 + 0] = H.x;
        part[ks][r][bg4 + 1] = H.y;
        part[ks][r][bg4 + 2] = H.z;
        part[ks][r][bg4 + 3] = H.w;
        __syncthreads();

        // ---- gates (wave 0) ----
        float hval = 0.f, cval = 0.f;
        if (tid < 64) {
            float gi = bias[0 + jj] + __uint_as_float((unsigned)u0 << 16);
            float gf = bias[2 + jj] + __uint_as_float((unsigned)u1 << 16);
            float gg = bias[4 + jj] + __uint_as_float((unsigned)u2 << 16);
            float go = bias[6 + jj] + __uint_as_float((unsigned)u3 << 16);
#pragma unroll
            for (int kk = 0; kk < NKS; ++kk) {
                gi += part[kk][0 + jj][bb];
                gf += part[kk][2 + jj][bb];
                gg += part[kk][4 + jj][bb];
                go += part[kk][6 + jj][bb];
            }
            float ig = 1.f / (1.f + __expf(-gi));
            float fg = 1.f / (1.f + __expf(-gf));
            float g  = tanhf(gg);
            float og = 1.f / (1.f + __expf(-go));
            float c  = fg * cst[tid] + ig * g;
            cst[tid] = c;
            float h  = og * tanhf(c);
            hval = h; cval = c;
            int j = (bj << 1) + jj;
            __hip_atomic_store(hbuf + (size_t)((t + 1) & 1) * (HID * BATCH) + (size_t)j * BATCH + bb,
                               h, __ATOMIC_RELAXED, __HIP_MEMORY_SCOPE_AGENT);
        }

        asm volatile("s_waitcnt vmcnt(0)" ::: "memory");
        if (tid == 0) {
            __hip_atomic_fetch_add(&garr[(bj & 7) * 32], 1, __ATOMIC_RELAXED,
                                   __HIP_MEMORY_SCOPE_AGENT);
        }

        // out stores off the critical chain
        if (tid < 64) {
            int j = (bj << 1) + jj;
            out[((size_t)t * BATCH + bb) * HID + j] = hval;
            if (t == T_STEPS - 1) {
                out[(size_t)T_STEPS * BATCH * HID + (size_t)bb * HID + j] = hval;
                out[(size_t)T_STEPS * BATCH * HID + (size_t)BATCH * HID + (size_t)bb * HID + j] = cval;
            }
        }
    }
}

// ============================================================================
// Fallback (R4 kernel, verbatim): used when ws_size can't hold x_proj
// ============================================================================
__global__ __launch_bounds__(NTHR, 1) void lstm_persist_full(
    const float* __restrict__ x, const float* __restrict__ Wih,
    const float* __restrict__ Whh,
    const float* __restrict__ bih, const float* __restrict__ bhh,
    float* __restrict__ out, float* hbuf, int* barr)
{
    __shared__ float Wl[8][WSTRIDE_F];
    __shared__ float hl[HID][HSTRIDE];
    __shared__ float part[NKS][8][33];
    __shared__ float bias[8];
    __shared__ float cst[JB * BATCH];

    const int tid = threadIdx.x;
    const int bj  = blockIdx.x;
    const int r   = tid & 7;
    const int bg  = (tid >> 3) & 7;
    const int ks  = tid >> 6;
    const int bg4 = bg * 4;
    const int k0  = ks * 16;

    for (int i = tid; i < 8 * 256; i += NTHR) {
        int row = i >> 8, q = i & 255;
        int R = ((row >> 1) << 9) + (bj << 1) + (row & 1);
        float4 v = (q < 128) ? ((const float4*)(Wih + (size_t)R * DIM))[q]
                             : ((const float4*)(Whh + (size_t)R * HID))[q - 128];
        *(float4*)&Wl[row][q * 4] = v;
    }
    if (tid < 8) {
        int R = ((tid >> 1) << 9) + (bj << 1) + (tid & 1);
        bias[tid] = bih[R] + bhh[R];
    }
    if (tid < JB * BATCH) cst[tid] = 0.f;
    __syncthreads();

    const float4* __restrict__ wrow = (const float4*)&Wl[r][0];
    int* garr = barr;
    int* gctr = barr + 8 * 32;
    int* rel  = barr + 8 * 32 + 32;

    for (int t = 0; t < T_STEPS; ++t) {
        float4 A0 = {0,0,0,0}, A1 = {0,0,0,0}, A2 = {0,0,0,0}, A3 = {0,0,0,0};
        {
            const float* xb = x + ((size_t)t * BATCH + bg4) * DIM;
            const float4* v0 = (const float4*)xb;
            const float4* v1 = (const float4*)(xb + DIM);
            const float4* v2 = (const float4*)(xb + 2 * DIM);
            const float4* v3 = (const float4*)(xb + 3 * DIM);
#pragma unroll 4
            for (int k = 0; k < 16; ++k) {
                float4 w = wrow[k0 + k];
                float4 p0 = v0[k0 + k], p1 = v1[k0 + k], p2 = v2[k0 + k], p3 = v3[k0 + k];
                FMA4(A0, w, p0); FMA4(A1, w, p1); FMA4(A2, w, p2); FMA4(A3, w, p3);
            }
        }
        if (tid == 0) {
            while (__hip_atomic_load(rel, __ATOMIC_RELAXED, __HIP_MEMORY_SCOPE_AGENT) < t)
                __builtin_amdgcn_s_sleep(1);
        }
        __syncthreads();
        {
            const float* hsrc = hbuf + (size_t)(t & 1) * (HID * BATCH) + (tid << 2);
            float4 v0, v1, v2, v3, v4, v5, v6, v7;
            LLC_LOAD4(v0, hsrc);
            LLC_LOAD4(v1, hsrc + 2048);
            LLC_LOAD4(v2, hsrc + 4096);
            LLC_LOAD4(v3, hsrc + 6144);
            LLC_LOAD4(v4, hsrc + 8192);
            LLC_LOAD4(v5, hsrc + 10240);
            LLC_LOAD4(v6, hsrc + 12288);
            LLC_LOAD4(v7, hsrc + 14336);
            asm volatile("s_waitcnt vmcnt(0)" ::: "memory");
            __builtin_amdgcn_sched_barrier(0);
            float* wp = &hl[tid >> 3][(tid & 7) << 2];
            *(float4*)(wp + 0 * 64 * HSTRIDE) = v0;
            *(float4*)(wp + 1 * 64 * HSTRIDE) = v1;
            *(float4*)(wp + 2 * 64 * HSTRIDE) = v2;
            *(float4*)(wp + 3 * 64 * HSTRIDE) = v3;
            *(float4*)(wp + 4 * 64 * HSTRIDE) = v4;
            *(float4*)(wp + 5 * 64 * HSTRIDE) = v5;
            *(float4*)(wp + 6 * 64 * HSTRIDE) = v6;
            *(float4*)(wp + 7 * 64 * HSTRIDE) = v7;
        }
        __syncthreads();
        float4 H = {0,0,0,0};
#pragma unroll 4
        for (int kq = 0; kq < 16; ++kq) {
            int K = (ks << 6) + (kq << 2);
            float4 w4 = *(const float4*)&Wl[r][512 + K];
            float4 h0 = *(const float4*)&hl[K + 0][bg4];
            float4 h1 = *(const float4*)&hl[K + 1][bg4];
            float4 h2 = *(const float4*)&hl[K + 2][bg4];
            float4 h3 = *(const float4*)&hl[K + 3][bg4];
            FMAS(H, w4.x, h0); FMAS(H, w4.y, h1); FMAS(H, w4.z, h2); FMAS(H, w4.w, h3);
        }
        part[ks][r][bg4 + 0] = hsum4(A0) + H.x;
        part[ks][r][bg4 + 1] = hsum4(A1) + H.y;
        part[ks][r][bg4 + 2] = hsum4(A2) + H.z;
        part[ks][r][bg4 + 3] = hsum4(A3) + H.w;
        __syncthreads();
        float hval = 0.f, cval = 0.f;
        if (tid < JB * BATCH) {
            int jj = tid & 1, b = tid >> 1;
            float gi = bias[0 + jj], gf = bias[2 + jj], gg = bias[4 + jj], go = bias[6 + jj];
#pragma unroll
            for (int kk = 0; kk < NKS; ++kk) {
                gi += part[kk][0 + jj][b];
                gf += part[kk][2 + jj][b];
                gg += part[kk][4 + jj][b];
                go += part[kk][6 + jj][b];
            }
            float ig = 1.f / (1.f + __expf(-gi));
            float fg = 1.f / (1.f + __expf(-gf));
            float g  = tanhf(gg);
            float og = 1.f / (1.f + __expf(-go));
            float c  = fg * cst[tid] + ig * g;
            cst[tid] = c;
            float h  = og * tanhf(c);
            hval = h; cval = c;
            int j = (bj << 1) + jj;
            __hip_atomic_store(hbuf + (size_t)((t + 1) & 1) * (HID * BATCH) + (size_t)j * BATCH + b,
                               h, __ATOMIC_RELAXED, __HIP_MEMORY_SCOPE_AGENT);
        }
        asm volatile("s_waitcnt vmcnt(0)" ::: "memory");
        if (tid == 0) {
            int grp = bj & 7;
            int old = __hip_atomic_fetch_add(&garr[grp * 32], 1, __ATOMIC_RELAXED,
                                             __HIP_MEMORY_SCOPE_AGENT);
            if (old == (t + 1) * 32 - 1) {
                int o2 = __hip_atomic_fetch_add(gctr, 1, __ATOMIC_RELAXED,
                                                __HIP_MEMORY_SCOPE_AGENT);
                if (o2 == (t + 1) * 8 - 1) {
                    __hip_atomic_fetch_add(rel, 1, __ATOMIC_RELAXED,
                                           __HIP_MEMORY_SCOPE_AGENT);
                }
            }
        }
        if (tid < JB * BATCH) {
            int jj = tid & 1, b = tid >> 1;
            int j = (bj << 1) + jj;
            out[((size_t)t * BATCH + b) * HID + j] = hval;
            if (t == T_STEPS - 1) {
                out[(size_t)T_STEPS * BATCH * HID + (size_t)b * HID + j] = hval;
                out[(size_t)T_STEPS * BATCH * HID + (size_t)BATCH * HID + (size_t)b * HID + j] = cval;
            }
        }
    }
}

extern "C" void kernel_launch(void* const* d_in, const int* in_sizes, int n_in,
                              void* d_out, int out_size, void* d_ws, size_t ws_size,
                              hipStream_t stream) {
    (void)in_sizes; (void)n_in; (void)out_size;
    const float* x   = (const float*)d_in[0];
    const float* Wih = (const float*)d_in[1];
    const float* Whh = (const float*)d_in[2];
    const float* bih = (const float*)d_in[3];
    const float* bhh = (const float*)d_in[4];
    float* outp = (float*)d_out;
    float* hbuf = (float*)d_ws;
    int*   barr = (int*)((char*)d_ws + HBUF_BYTES);

    hipMemsetAsync(d_ws, 0, HBUF_BYTES + BARR_BYTES, stream);

    const size_t need = (size_t)HBUF_BYTES + BARR_BYTES + XP_BYTES;
    if (ws_size >= need) {
        unsigned short* xp = (unsigned short*)((char*)d_ws + HBUF_BYTES + BARR_BYTES);
        xproj_gemm<<<(MROWS / 64) * (NCOLS / 64), 256, 0, stream>>>(x, Wih, xp);
        lstm_persist_xp<<<NB, NTHR, 0, stream>>>(xp, Whh, bih, bhh, outp, hbuf, barr);
    } else {
        lstm_persist_full<<<NB, NTHR, 0, stream>>>(x, Wih, Whh, bih, bhh, outp, hbuf, barr);
    }
}